// Round 2
// baseline (1061.440 us; speedup 1.0000x reference)
//
#include <hip/hip_runtime.h>

typedef __bf16 bf16x8 __attribute__((ext_vector_type(8)));
typedef float  f32x4  __attribute__((ext_vector_type(4)));
typedef unsigned int u32x4 __attribute__((ext_vector_type(4)));

#define MFMA(a, b, c) __builtin_amdgcn_mfma_f32_16x16x32_bf16((a), (b), (c), 0, 0, 0)

#define THREADS 512
#define WAVES   8
#define CPW     4     // crystals per wave
#define CPB     32    // crystals per block (8 waves x 4)
#define MT      32    // nodes per tile (2 x 16-row MFMA subtiles)

// workspace layout: [seg table][bf16 weight pack]
#define SEG_INTS  16416              // >= S+1, 16B-aligned
#define SEG_BYTES (SEG_INTS * 4)
#define O_WM1 0
#define O_WM2 65536
#define O_WA1 131072
#define O_WA2 262144
#define W_ELEMS 262656

// LDS weight region byte offsets (within wlds, per-head)
#define LA1B 0        // Wa1: 128 rows x 512 B (256 bf16)
#define LM1B 65536    // Wm1: 128 rows x 256 B
#define LM2B 98304    // Wm2: 128 rows x 256 B  (end 131072)

__device__ __forceinline__ bf16x8 cvt8(const float* pf) {
    float4 a = *(const float4*)pf, b = *(const float4*)(pf + 4);
    bf16x8 o;
    o[0] = (__bf16)a.x; o[1] = (__bf16)a.y; o[2] = (__bf16)a.z; o[3] = (__bf16)a.w;
    o[4] = (__bf16)b.x; o[5] = (__bf16)b.y; o[6] = (__bf16)b.z; o[7] = (__bf16)b.w;
    return o;
}

__device__ __forceinline__ unsigned pk2(float a, float b) {
    unsigned short ua = __builtin_bit_cast(unsigned short, (__bf16)a);
    unsigned short ub = __builtin_bit_cast(unsigned short, (__bf16)b);
    return (unsigned)ua | ((unsigned)ub << 16);
}

__device__ __forceinline__ int lower_bound(const int* __restrict__ a, int n, int v) {
    int lo = 0, hi = n;
    while (lo < hi) { int mid = (lo + hi) >> 1; if (a[mid] < v) lo = mid + 1; else hi = mid; }
    return lo;
}

// ---------------------------------------------------------------------------
// Prep 1: pack 4 f32 weight tensors into contiguous bf16.
// ---------------------------------------------------------------------------
__global__ __launch_bounds__(256) void prep_kernel(
    const float* __restrict__ Wm1, const float* __restrict__ Wm2,
    const float* __restrict__ Wa1, const float* __restrict__ Wa2,
    __bf16* __restrict__ wb)
{
    int i8 = blockIdx.x * 256 + threadIdx.x;
    if (i8 >= W_ELEMS / 8) return;
    int i = i8 * 8;
    const float* src; int s;
    if      (i < O_WM2) { src = Wm1; s = i; }
    else if (i < O_WA1) { src = Wm2; s = i - O_WM2; }
    else if (i < O_WA2) { src = Wa1; s = i - O_WA1; }
    else                { src = Wa2; s = i - O_WA2; }
    *(bf16x8*)(wb + i) = cvt8(src + s);
}

// ---------------------------------------------------------------------------
// Prep 2: segment-start table seg[c] = lower_bound(index, c), c = 0..S.
// ---------------------------------------------------------------------------
__global__ __launch_bounds__(256) void seg_kernel(
    const int* __restrict__ index, int N, int S, int* __restrict__ seg)
{
    int c = blockIdx.x * 256 + threadIdx.x;
    if (c <= S) seg[c] = lower_bound(index, N, c);
}

// ---------------------------------------------------------------------------
// Fused kernel, weight-stationary. Block = one head x 32 crystals.
// 8 waves; wave w independently owns crystals [c0+4w, c0+4w+4): no main-loop
// barriers. Head's weights staged once in LDS (XOR-swizzled, slot^=row&7).
// GEMM3 normal (cry half precomputed per-crystal, used as acc-init);
// GEMM1 swapped (A=Wm1,B=fea) + in-register shuffle repack -> GEMM2 normal.
// MFMA 16x16x32 bf16: A/B[idx=lane&15][k=(lane>>4)*8+j]; D col=lane&15,
// row=(lane>>4)*4+reg.
// ---------------------------------------------------------------------------
template<bool WB, bool SEG>
__global__ __launch_bounds__(THREADS, 2) void fused3_kernel(
    const float* __restrict__ fea, const float* __restrict__ cry,
    const float* __restrict__ Wm1, const float* __restrict__ bm1,
    const float* __restrict__ Wm2, const float* __restrict__ bm2,
    const float* __restrict__ Wa1, const float* __restrict__ ba1,
    const float* __restrict__ Wa2, const float* __restrict__ ba2,
    const __bf16* __restrict__ wb, const int* __restrict__ seg,
    const int* __restrict__ index, int N, int S, float* __restrict__ out)
{
    __shared__ __align__(16) __bf16 wlds[65536];      // 128 KiB weights
    __shared__ float crylds[WAVES][CPW][128];          // 16 KiB cry.Wa1cry^T
    __shared__ float bm1lds[128];                      // 512 B

    const int h  = blockIdx.x & 3;
    const int c0 = (blockIdx.x >> 2) * CPB;
    const int t  = threadIdx.x;
    const int lane = t & 63, w = t >> 6, ml = lane & 15, q = lane >> 4;
    const int swzb = (ml & 7) << 4;
    const char* wbytes = (const char*)wlds;

    // ---- stage weights (swizzled source -> linear LDS) ----
#pragma unroll
    for (int i = 0; i < 16; i++) {
        const int cb = (t + i * THREADS) << 4;   // chunk byte in [0,131072)
        int local, row, slot, rowE; size_t wboff; const float* basef;
        if (cb < LM1B)      { local = cb;        row = local >> 9; slot = (local >> 4) & 31; rowE = 256; wboff = (size_t)O_WA1 + (size_t)h * 32768; basef = Wa1 + (size_t)h * 32768; }
        else if (cb < LM2B) { local = cb - LM1B; row = local >> 8; slot = (local >> 4) & 15; rowE = 128; wboff = (size_t)O_WM1 + (size_t)h * 16384; basef = Wm1 + (size_t)h * 16384; }
        else                { local = cb - LM2B; row = local >> 8; slot = (local >> 4) & 15; rowE = 128; wboff = (size_t)O_WM2 + (size_t)h * 16384; basef = Wm2 + (size_t)h * 16384; }
        size_t off = (size_t)row * rowE + (size_t)((slot ^ (row & 7)) << 3);
        bf16x8 v;
        if constexpr (WB) v = *(const bf16x8*)(wb + wboff + off);
        else              v = cvt8(basef + off);
        *(bf16x8*)((char*)wlds + cb) = v;
    }
    if (t < 32) *(float4*)&bm1lds[t * 4] = *(const float4*)&bm1[h * 128 + t * 4];
    __syncthreads();

    // ---- per-wave crystal range ----
    const int cw0 = min(c0 + w * CPW, S);
    const int cw1 = min(cw0 + CPW, S);
    int start, end;
    if constexpr (SEG) { start = seg[cw0]; end = seg[cw1]; }
    else { start = lower_bound(index, N, cw0); end = lower_bound(index, N, cw1); }

    // ---- hoisted per-lane biases (col = ot*16+ml of head h) ----
    float ba1v[8], bb2[8], wa2v[8];
#pragma unroll
    for (int ot = 0; ot < 8; ot++) {
        ba1v[ot] = ba1[h * 128 + ot * 16 + ml];
        bb2[ot]  = bm2[h * 128 + ot * 16 + ml];
        wa2v[ot] = Wa2[h * 128 + ot * 16 + ml];
    }
    const float ba2v = ba2[h];

    // ---- precompute cry contribution: D[crystal r][o] = cry_c . Wa1cry^T ----
    {
        bf16x8 cf[4];
#pragma unroll
        for (int kk = 0; kk < 4; kk++) {
            if (ml < CPW && cw0 + ml < S) cf[kk] = cvt8(cry + (size_t)(cw0 + ml) * 128 + kk * 32 + q * 8);
            else { bf16x8 z; for (int j = 0; j < 8; j++) z[j] = (__bf16)0.f; cf[kk] = z; }
        }
#pragma unroll
        for (int ot = 0; ot < 8; ot++) {
            f32x4 acc = {0.f, 0.f, 0.f, 0.f};
#pragma unroll
            for (int kk = 0; kk < 4; kk++) {
                bf16x8 B = *(const bf16x8*)(wbytes + LA1B + (ot * 16 + ml) * 512 + ((((16 + kk * 4 + q) << 4)) ^ swzb));
                acc = MFMA(cf[kk], B, acc);
            }
            if (q == 0) {
#pragma unroll
                for (int r = 0; r < 4; r++) crylds[w][r][ot * 16 + ml] = acc[r];
            }
        }
    }

    float m_run = -1e30f, d_run = 0.f;
    float wacc[8] = {0.f,0.f,0.f,0.f,0.f,0.f,0.f,0.f};
    int cur_c = -1, emit_c = cw0;

    auto flushf = [&]() {
        float inv = 1.f / (d_run + 1e-16f);
        for (int z = emit_c; z < cur_c; z++)   // zero-fill empty crystals
            *(float2*)&out[(size_t)z * 512 + h * 128 + lane * 2] = make_float2(0.f, 0.f);
#pragma unroll
        for (int ot = 0; ot < 8; ot++) {
            float v = wacc[ot];
            v += __shfl_xor(v, 16);
            v += __shfl_xor(v, 32);
            if (q == 0) out[(size_t)cur_c * 512 + h * 128 + ot * 16 + ml] = v * inv;
            wacc[ot] = 0.f;
        }
        emit_c = cur_c + 1;
        m_run = -1e30f; d_run = 0.f;
    };

    for (int tb = start; tb < end; tb += MT) {
        int nv = end - tb; if (nv > MT) nv = MT;

        // ---- per-lane node index (rows 0..31 on lanes 0..31) ----
        const int iv = (lane < nv) ? index[tb + lane] : cw0;

        // ---- fea A/B fragments (zero-pad invalid rows) ----
        bf16x8 af[2][4];
#pragma unroll
        for (int s = 0; s < 2; s++) {
            const int row = s * 16 + ml;
            const bool val = row < nv;
            const float* p = fea + (size_t)(tb + row) * 128 + q * 8;
#pragma unroll
            for (int kk = 0; kk < 4; kk++) {
                if (val) af[s][kk] = cvt8(p + kk * 32);
                else { bf16x8 z; for (int j = 0; j < 8; j++) z[j] = (__bf16)0.f; af[s][kk] = z; }
            }
        }

        // ---- crystal-local id per output row (for cry acc-init) ----
        int cl[2][4];
#pragma unroll
        for (int s = 0; s < 2; s++)
#pragma unroll
        for (int r = 0; r < 4; r++)
            cl[s][r] = __shfl(iv, s * 16 + q * 4 + r) - cw0;

        // ---- GEMM3 (node half) + in-register logits ----
        float lsum[8] = {0.f,0.f,0.f,0.f,0.f,0.f,0.f,0.f};
#pragma unroll
        for (int ot = 0; ot < 8; ot++) {
            bf16x8 B[4];
#pragma unroll
            for (int kk = 0; kk < 4; kk++)
                B[kk] = *(const bf16x8*)(wbytes + LA1B + (ot * 16 + ml) * 512 + ((((kk * 4 + q) << 4)) ^ swzb));
            const int oc = ot * 16 + ml;
#pragma unroll
            for (int s = 0; s < 2; s++) {
                f32x4 acc;
#pragma unroll
                for (int r = 0; r < 4; r++) acc[r] = crylds[w][cl[s][r]][oc];
#pragma unroll
                for (int kk = 0; kk < 4; kk++) acc = MFMA(af[s][kk], B[kk], acc);
#pragma unroll
                for (int r = 0; r < 4; r++) {
                    float v = acc[r] + ba1v[ot]; v = v >= 0.f ? v : 0.01f * v;
                    lsum[s * 4 + r] += v * wa2v[ot];
                }
            }
        }
        float lv[8];
#pragma unroll
        for (int sl = 0; sl < 8; sl++) {
            float x = lsum[sl];
            x += __shfl_xor(x, 1); x += __shfl_xor(x, 2);
            x += __shfl_xor(x, 4); x += __shfl_xor(x, 8);
            lv[sl] = x + ba2v;   // logit of row (sl>>2)*16 + q*4 + (sl&3)
        }

        // ---- GEMM1 swapped (A=Wm1, B=fea) + in-register repack -> a2 ----
        bf16x8 a2[2][4];
#pragma unroll
        for (int kk = 0; kk < 4; kk++) {
            unsigned pw[2][2][2];   // [otl][s][p]
#pragma unroll
            for (int otl = 0; otl < 2; otl++) {
                const int ot = kk * 2 + otl;
                bf16x8 A[4];
#pragma unroll
                for (int k4 = 0; k4 < 4; k4++)
                    A[k4] = *(const bf16x8*)(wbytes + LM1B + (ot * 16 + ml) * 256 + ((((k4 * 4 + q) << 4)) ^ swzb));
                const float4 bq = *(const float4*)&bm1lds[ot * 16 + q * 4];
#pragma unroll
                for (int s = 0; s < 2; s++) {
                    f32x4 acc = {0.f, 0.f, 0.f, 0.f};
#pragma unroll
                    for (int k4 = 0; k4 < 4; k4++) acc = MFMA(A[k4], af[s][k4], acc);
                    float v0 = acc[0] + bq.x, v1 = acc[1] + bq.y;
                    float v2 = acc[2] + bq.z, v3 = acc[3] + bq.w;
                    v0 = v0 >= 0.f ? v0 : 0.01f * v0;  v1 = v1 >= 0.f ? v1 : 0.01f * v1;
                    v2 = v2 >= 0.f ? v2 : 0.01f * v2;  v3 = v3 >= 0.f ? v3 : 0.01f * v3;
                    pw[otl][s][0] = pk2(v0, v1);
                    pw[otl][s][1] = pk2(v2, v3);
                }
            }
            const int srcLo = (((2 * q) & 3) << 4) + ml;
            const int srcHi = (((2 * q + 1) & 3) << 4) + ml;
            const bool hiSel = (q >> 1) & 1;
#pragma unroll
            for (int s = 0; s < 2; s++) {
                unsigned l0a = (unsigned)__shfl((int)pw[0][s][0], srcLo);
                unsigned l0b = (unsigned)__shfl((int)pw[1][s][0], srcLo);
                unsigned l1a = (unsigned)__shfl((int)pw[0][s][1], srcLo);
                unsigned l1b = (unsigned)__shfl((int)pw[1][s][1], srcLo);
                unsigned h0a = (unsigned)__shfl((int)pw[0][s][0], srcHi);
                unsigned h0b = (unsigned)__shfl((int)pw[1][s][0], srcHi);
                unsigned h1a = (unsigned)__shfl((int)pw[0][s][1], srcHi);
                unsigned h1b = (unsigned)__shfl((int)pw[1][s][1], srcHi);
                u32x4 wv4 = { hiSel ? l0b : l0a, hiSel ? l1b : l1a,
                              hiSel ? h0b : h0a, hiSel ? h1b : h1a };
                a2[s][kk] = __builtin_bit_cast(bf16x8, wv4);
            }
        }

        // ---- GEMM2 (bias-initialized accumulators, kept in registers) ----
        f32x4 acc2[2][8];
#pragma unroll
        for (int ot = 0; ot < 8; ot++) {
            bf16x8 B[4];
#pragma unroll
            for (int kk = 0; kk < 4; kk++)
                B[kk] = *(const bf16x8*)(wbytes + LM2B + (ot * 16 + ml) * 256 + ((((kk * 4 + q) << 4)) ^ swzb));
#pragma unroll
            for (int s = 0; s < 2; s++) {
                f32x4 acc = {bb2[ot], bb2[ot], bb2[ot], bb2[ot]};
#pragma unroll
                for (int kk = 0; kk < 4; kk++) acc = MFMA(a2[s][kk], B[kk], acc);
                acc2[s][ot] = acc;
            }
        }

        // ---- run walk: per-crystal online softmax + weighted accumulation ----
        unsigned long long bmask;
        {
            int ivp = __shfl(iv, lane > 0 ? lane - 1 : 0);
            bmask = __ballot(lane < nv && (lane == 0 || iv != ivp));
        }
        while (bmask) {
            int a = (int)__builtin_ctzll(bmask);
            bmask &= bmask - 1;
            int b = bmask ? (int)__builtin_ctzll(bmask) : nv;
            int c = __shfl(iv, a);
            if (c != cur_c) {
                if (cur_c >= 0) flushf();
                cur_c = c;
            }
            float tmax = -1e30f;
#pragma unroll
            for (int sl = 0; sl < 8; sl++) {
                int row = (sl >> 2) * 16 + q * 4 + (sl & 3);
                if (row >= a && row < b) tmax = fmaxf(tmax, lv[sl]);
            }
            tmax = fmaxf(tmax, __shfl_xor(tmax, 16));
            tmax = fmaxf(tmax, __shfl_xor(tmax, 32));
            float m_new = fmaxf(m_run, tmax);
            float scf = __expf(m_run - m_new);
            d_run *= scf;
#pragma unroll
            for (int ot = 0; ot < 8; ot++) wacc[ot] *= scf;
            m_run = m_new;

            float wv[8]; float dp = 0.f;
#pragma unroll
            for (int sl = 0; sl < 8; sl++) {
                int row = (sl >> 2) * 16 + q * 4 + (sl & 3);
                float ww = (row >= a && row < b) ? __expf(lv[sl] - m_run) : 0.f;
                wv[sl] = ww; dp += ww;
            }
            dp += __shfl_xor(dp, 16);
            dp += __shfl_xor(dp, 32);
            d_run += dp;
#pragma unroll
            for (int ot = 0; ot < 8; ot++) {
                float s = 0.f;
#pragma unroll
                for (int sl = 0; sl < 8; sl++)
                    s += wv[sl] * acc2[sl >> 2][ot][sl & 3];
                wacc[ot] += s;
            }
        }
    }

    if (cur_c >= 0) flushf();
    for (int z = emit_c; z < cw1; z++)   // trailing empty crystals
        *(float2*)&out[(size_t)z * 512 + h * 128 + lane * 2] = make_float2(0.f, 0.f);
}

// ---------------------------------------------------------------------------
extern "C" void kernel_launch(void* const* d_in, const int* in_sizes, int n_in,
                              void* d_out, int out_size, void* d_ws, size_t ws_size,
                              hipStream_t stream)
{
    const float* fea = (const float*)d_in[0];
    const float* cry = (const float*)d_in[1];
    const float* Wm1 = (const float*)d_in[2];
    const float* bm1 = (const float*)d_in[3];
    const float* Wm2 = (const float*)d_in[4];
    const float* bm2 = (const float*)d_in[5];
    const float* Wa1 = (const float*)d_in[6];
    const float* ba1 = (const float*)d_in[7];
    const float* Wa2 = (const float*)d_in[8];
    const float* ba2 = (const float*)d_in[9];
    const int* index = (const int*)d_in[10];

    const int N = in_sizes[0] / 128;      // 200000
    const int S = out_size / 512;         // 16384
    const int grid = 4 * ((S + CPB - 1) / CPB);

    const size_t needSeg  = (size_t)SEG_BYTES;
    const size_t needFull = needSeg + (size_t)W_ELEMS * 2;

    if (ws_size >= needFull) {
        int* seg = (int*)d_ws;
        __bf16* wbp = (__bf16*)((char*)d_ws + SEG_BYTES);
        seg_kernel<<<(S + 1 + 255) / 256, 256, 0, stream>>>(index, N, S, seg);
        prep_kernel<<<(W_ELEMS / 8 + 255) / 256, 256, 0, stream>>>(Wm1, Wm2, Wa1, Wa2, wbp);
        fused3_kernel<true, true><<<grid, THREADS, 0, stream>>>(
            fea, cry, Wm1, bm1, Wm2, bm2, Wa1, ba1, Wa2, ba2,
            wbp, seg, index, N, S, (float*)d_out);
    } else if (ws_size >= needSeg) {
        int* seg = (int*)d_ws;
        seg_kernel<<<(S + 1 + 255) / 256, 256, 0, stream>>>(index, N, S, seg);
        fused3_kernel<false, true><<<grid, THREADS, 0, stream>>>(
            fea, cry, Wm1, bm1, Wm2, bm2, Wa1, ba1, Wa2, ba2,
            nullptr, seg, index, N, S, (float*)d_out);
    } else {
        fused3_kernel<false, false><<<grid, THREADS, 0, stream>>>(
            fea, cry, Wm1, bm1, Wm2, bm2, Wa1, ba1, Wa2, ba2,
            nullptr, nullptr, index, N, S, (float*)d_out);
    }
}

// Round 3
// 411.279 us; speedup vs baseline: 2.5808x; 2.5808x over previous
//
#include <hip/hip_runtime.h>

typedef __bf16 bf16x8 __attribute__((ext_vector_type(8)));
typedef float  f32x4  __attribute__((ext_vector_type(4)));
typedef unsigned int u32x4 __attribute__((ext_vector_type(4)));

#define MFMA(a, b, c) __builtin_amdgcn_mfma_f32_16x16x32_bf16((a), (b), (c), 0, 0, 0)

#define THREADS 512
#define WAVES   8
#define CPW     4     // crystals per wave
#define CPB     32    // crystals per block (8 waves x 4)
#define MT      32    // nodes per tile (2 x 16-row halves)

// workspace layout: [seg table][bf16 weight pack][bf16 cry][bf16 fea]
#define SEG_INTS  16416
#define SEG_BYTES (SEG_INTS * 4)       // 65664
#define O_WM1 0
#define O_WM2 65536
#define O_WA1 131072
#define O_WA2 262144
#define W_ELEMS 262656
#define W_BYTES (W_ELEMS * 2)          // 525312

// LDS weight region byte offsets (within wlds, per-head)
#define LA1B 0        // Wa1: 128 rows x 512 B
#define LM1B 65536    // Wm1: 128 rows x 256 B
#define LM2B 98304    // Wm2: 128 rows x 256 B  (end 131072)

__device__ __forceinline__ bf16x8 cvt8(const float* pf) {
    float4 a = *(const float4*)pf, b = *(const float4*)(pf + 4);
    bf16x8 o;
    o[0] = (__bf16)a.x; o[1] = (__bf16)a.y; o[2] = (__bf16)a.z; o[3] = (__bf16)a.w;
    o[4] = (__bf16)b.x; o[5] = (__bf16)b.y; o[6] = (__bf16)b.z; o[7] = (__bf16)b.w;
    return o;
}

__device__ __forceinline__ unsigned pk2(float a, float b) {
    unsigned short ua = __builtin_bit_cast(unsigned short, (__bf16)a);
    unsigned short ub = __builtin_bit_cast(unsigned short, (__bf16)b);
    return (unsigned)ua | ((unsigned)ub << 16);
}

__device__ __forceinline__ int lower_bound(const int* __restrict__ a, int n, int v) {
    int lo = 0, hi = n;
    while (lo < hi) { int mid = (lo + hi) >> 1; if (a[mid] < v) lo = mid + 1; else hi = mid; }
    return lo;
}

// ---------------------------------------------------------------------------
// Prep 1: pack 4 f32 weight tensors into contiguous bf16.
// ---------------------------------------------------------------------------
__global__ __launch_bounds__(256) void prep_kernel(
    const float* __restrict__ Wm1, const float* __restrict__ Wm2,
    const float* __restrict__ Wa1, const float* __restrict__ Wa2,
    __bf16* __restrict__ wb)
{
    int i8 = blockIdx.x * 256 + threadIdx.x;
    if (i8 >= W_ELEMS / 8) return;
    int i = i8 * 8;
    const float* src; int s;
    if      (i < O_WM2) { src = Wm1; s = i; }
    else if (i < O_WA1) { src = Wm2; s = i - O_WM2; }
    else if (i < O_WA2) { src = Wa1; s = i - O_WA1; }
    else                { src = Wa2; s = i - O_WA2; }
    *(bf16x8*)(wb + i) = cvt8(src + s);
}

// ---------------------------------------------------------------------------
// Prep 2: segment-start table seg[c] = lower_bound(index, c), c = 0..S.
// ---------------------------------------------------------------------------
__global__ __launch_bounds__(256) void seg_kernel(
    const int* __restrict__ index, int N, int S, int* __restrict__ seg)
{
    int c = blockIdx.x * 256 + threadIdx.x;
    if (c <= S) seg[c] = lower_bound(index, N, c);
}

// ---------------------------------------------------------------------------
// Prep 3: cast f32 -> bf16 (8 elems/thread). Rounding identical to in-kernel
// cvt8, so results are bitwise-unchanged.
// ---------------------------------------------------------------------------
__global__ __launch_bounds__(256) void cast_kernel(
    const float* __restrict__ src, __bf16* __restrict__ dst, int n8)
{
    int i = blockIdx.x * 256 + threadIdx.x;
    if (i < n8) *(bf16x8*)(dst + (size_t)i * 8) = cvt8(src + (size_t)i * 8);
}

// ---------------------------------------------------------------------------
// Fused kernel, weight-stationary, half-tile pipelined for register pressure.
// Block = one head x 32 crystals; 8 waves; wave w owns crystals
// [c0+4w, c0+4w+4): no main-loop barriers. Head's weights staged once in LDS
// (XOR-swizzled). Per 32-node tile, two 16-row halves are processed fully
// (GEMM3->logits, GEMM1 swapped + repack, GEMM2, softmax walk) before the
// next half, keeping peak live registers ~170 (no scratch spills).
// MFMA 16x16x32 bf16: A/B[idx=lane&15][k=(lane>>4)*8+j]; D col=lane&15,
// row=(lane>>4)*4+reg.
// ---------------------------------------------------------------------------
template<bool WB, bool SEG, bool FB>
__global__ __launch_bounds__(THREADS, 2) void fused4_kernel(
    const float* __restrict__ fea, const float* __restrict__ cry,
    const float* __restrict__ Wm1, const float* __restrict__ bm1,
    const float* __restrict__ Wm2, const float* __restrict__ bm2,
    const float* __restrict__ Wa1, const float* __restrict__ ba1,
    const float* __restrict__ Wa2, const float* __restrict__ ba2,
    const __bf16* __restrict__ wb, const int* __restrict__ seg,
    const __bf16* __restrict__ feab, const __bf16* __restrict__ cryb,
    const int* __restrict__ index, int N, int S, float* __restrict__ out)
{
    __shared__ __align__(16) __bf16 wlds[65536];      // 128 KiB weights
    __shared__ float crylds[WAVES][CPW][128];          // 16 KiB cry.Wa1cry^T
    __shared__ float bm1lds[128];                      // 512 B

    const int h  = blockIdx.x & 3;
    const int c0 = (blockIdx.x >> 2) * CPB;
    const int t  = threadIdx.x;
    const int lane = t & 63, w = t >> 6, ml = lane & 15, q = lane >> 4;
    const int swzb = (ml & 7) << 4;
    const char* wbytes = (const char*)wlds;

    // ---- stage weights (swizzled source -> linear LDS) ----
#pragma unroll
    for (int i = 0; i < 16; i++) {
        const int cb = (t + i * THREADS) << 4;   // chunk byte in [0,131072)
        int local, row, slot, rowE; size_t wboff; const float* basef;
        if (cb < LM1B)      { local = cb;        row = local >> 9; slot = (local >> 4) & 31; rowE = 256; wboff = (size_t)O_WA1 + (size_t)h * 32768; basef = Wa1 + (size_t)h * 32768; }
        else if (cb < LM2B) { local = cb - LM1B; row = local >> 8; slot = (local >> 4) & 15; rowE = 128; wboff = (size_t)O_WM1 + (size_t)h * 16384; basef = Wm1 + (size_t)h * 16384; }
        else                { local = cb - LM2B; row = local >> 8; slot = (local >> 4) & 15; rowE = 128; wboff = (size_t)O_WM2 + (size_t)h * 16384; basef = Wm2 + (size_t)h * 16384; }
        size_t off = (size_t)row * rowE + (size_t)((slot ^ (row & 7)) << 3);
        bf16x8 v;
        if constexpr (WB) v = *(const bf16x8*)(wb + wboff + off);
        else              v = cvt8(basef + off);
        *(bf16x8*)((char*)wlds + cb) = v;
    }
    if (t < 32) *(float4*)&bm1lds[t * 4] = *(const float4*)&bm1[h * 128 + t * 4];
    __syncthreads();

    // ---- per-wave crystal range ----
    const int cw0 = min(c0 + w * CPW, S);
    const int cw1 = min(cw0 + CPW, S);
    int start, end;
    if constexpr (SEG) { start = seg[cw0]; end = seg[cw1]; }
    else { start = lower_bound(index, N, cw0); end = lower_bound(index, N, cw1); }

    // ---- hoisted per-lane biases (col = ot*16+ml of head h) ----
    float ba1v[8], bb2[8], wa2v[8];
#pragma unroll
    for (int ot = 0; ot < 8; ot++) {
        ba1v[ot] = ba1[h * 128 + ot * 16 + ml];
        bb2[ot]  = bm2[h * 128 + ot * 16 + ml];
        wa2v[ot] = Wa2[h * 128 + ot * 16 + ml];
    }
    const float ba2v = ba2[h];

    // ---- precompute cry contribution: D[crystal r][o] = cry_c . Wa1cry^T ----
    {
        bf16x8 cf[4];
#pragma unroll
        for (int kk = 0; kk < 4; kk++) {
            bf16x8 z;
#pragma unroll
            for (int j = 0; j < 8; j++) z[j] = (__bf16)0.f;
            if (ml < CPW && cw0 + ml < S) {
                if constexpr (FB) z = *(const bf16x8*)(cryb + (size_t)(cw0 + ml) * 128 + kk * 32 + q * 8);
                else              z = cvt8(cry + (size_t)(cw0 + ml) * 128 + kk * 32 + q * 8);
            }
            cf[kk] = z;
        }
#pragma unroll
        for (int ot = 0; ot < 8; ot++) {
            f32x4 acc = {0.f, 0.f, 0.f, 0.f};
#pragma unroll
            for (int kk = 0; kk < 4; kk++) {
                bf16x8 B = *(const bf16x8*)(wbytes + LA1B + (ot * 16 + ml) * 512 + ((((16 + kk * 4 + q) << 4)) ^ swzb));
                acc = MFMA(cf[kk], B, acc);
            }
            if (q == 0) {
#pragma unroll
                for (int r = 0; r < 4; r++) crylds[w][r][ot * 16 + ml] = acc[r];
            }
        }
    }

    float m_run = -1e30f, d_run = 0.f;
    float wacc[8] = {0.f,0.f,0.f,0.f,0.f,0.f,0.f,0.f};
    int cur_c = -1, emit_c = cw0;

    auto flushf = [&]() {
        float inv = 1.f / (d_run + 1e-16f);
        for (int z = emit_c; z < cur_c; z++)   // zero-fill empty crystals
            *(float2*)&out[(size_t)z * 512 + h * 128 + lane * 2] = make_float2(0.f, 0.f);
#pragma unroll
        for (int ot = 0; ot < 8; ot++) {
            float v = wacc[ot];
            v += __shfl_xor(v, 16);
            v += __shfl_xor(v, 32);
            if (q == 0) out[(size_t)cur_c * 512 + h * 128 + ot * 16 + ml] = v * inv;
            wacc[ot] = 0.f;
        }
        emit_c = cur_c + 1;
        m_run = -1e30f; d_run = 0.f;
    };

    for (int tb = start; tb < end; tb += MT) {
        int nv = end - tb; if (nv > MT) nv = MT;

        // ---- per-lane node index (rows 0..31 on lanes 0..31) ----
        const int iv = (lane < nv) ? index[tb + lane] : cw0;

        // ---- run-boundary mask for the whole tile ----
        unsigned long long bmask;
        {
            int ivp = __shfl(iv, lane > 0 ? lane - 1 : 0);
            bmask = __ballot(lane < nv && (lane == 0 || iv != ivp));
        }

        // ---- two 16-row halves, fully processed in sequence ----
        for (int s = 0; s < 2; s++) {
            const int lo = s * 16;
            if (lo >= nv) break;
            int hcnt = nv - lo; if (hcnt > 16) hcnt = 16;

            // -- fea fragments for this half (zero-pad invalid rows) --
            bf16x8 afh[4];
            {
                const int row = lo + ml;
                const bool val = row < nv;
#pragma unroll
                for (int kk = 0; kk < 4; kk++) {
                    bf16x8 z;
#pragma unroll
                    for (int j = 0; j < 8; j++) z[j] = (__bf16)0.f;
                    if (val) {
                        if constexpr (FB) z = *(const bf16x8*)(feab + (size_t)(tb + row) * 128 + kk * 32 + q * 8);
                        else              z = cvt8(fea + (size_t)(tb + row) * 128 + kk * 32 + q * 8);
                    }
                    afh[kk] = z;
                }
            }

            // -- GEMM3 (node half of Wa1; cry half as acc-init) -> logits --
            float lv4[4];
            {
                int cl4[4];
#pragma unroll
                for (int r = 0; r < 4; r++)
                    cl4[r] = __shfl(iv, lo + q * 4 + r) - cw0;
                float lsum[4] = {0.f, 0.f, 0.f, 0.f};
#pragma unroll
                for (int ot = 0; ot < 8; ot++) {
                    bf16x8 B[4];
#pragma unroll
                    for (int kk = 0; kk < 4; kk++)
                        B[kk] = *(const bf16x8*)(wbytes + LA1B + (ot * 16 + ml) * 512 + ((((kk * 4 + q) << 4)) ^ swzb));
                    const int oc = ot * 16 + ml;
                    f32x4 acc;
#pragma unroll
                    for (int r = 0; r < 4; r++) acc[r] = crylds[w][cl4[r]][oc];
#pragma unroll
                    for (int kk = 0; kk < 4; kk++) acc = MFMA(afh[kk], B[kk], acc);
#pragma unroll
                    for (int r = 0; r < 4; r++) {
                        float v = acc[r] + ba1v[ot]; v = v >= 0.f ? v : 0.01f * v;
                        lsum[r] += v * wa2v[ot];
                    }
                }
#pragma unroll
                for (int rr = 0; rr < 4; rr++) {
                    float x = lsum[rr];
                    x += __shfl_xor(x, 1); x += __shfl_xor(x, 2);
                    x += __shfl_xor(x, 4); x += __shfl_xor(x, 8);
                    lv4[rr] = x + ba2v;   // logit of row lo + q*4 + rr
                }
            }

            // -- GEMM1 swapped (A=Wm1, B=fea half) + in-register repack --
            bf16x8 a2h[4];
#pragma unroll
            for (int kk = 0; kk < 4; kk++) {
                unsigned pw[2][2];   // [otl][p]
#pragma unroll
                for (int otl = 0; otl < 2; otl++) {
                    const int ot = kk * 2 + otl;
                    bf16x8 A[4];
#pragma unroll
                    for (int k4 = 0; k4 < 4; k4++)
                        A[k4] = *(const bf16x8*)(wbytes + LM1B + (ot * 16 + ml) * 256 + ((((k4 * 4 + q) << 4)) ^ swzb));
                    const float4 bq = *(const float4*)&bm1lds[ot * 16 + q * 4];
                    f32x4 acc = {0.f, 0.f, 0.f, 0.f};
#pragma unroll
                    for (int k4 = 0; k4 < 4; k4++) acc = MFMA(A[k4], afh[k4], acc);
                    float v0 = acc[0] + bq.x, v1 = acc[1] + bq.y;
                    float v2 = acc[2] + bq.z, v3 = acc[3] + bq.w;
                    v0 = v0 >= 0.f ? v0 : 0.01f * v0;  v1 = v1 >= 0.f ? v1 : 0.01f * v1;
                    v2 = v2 >= 0.f ? v2 : 0.01f * v2;  v3 = v3 >= 0.f ? v3 : 0.01f * v3;
                    pw[otl][0] = pk2(v0, v1);
                    pw[otl][1] = pk2(v2, v3);
                }
                const int srcLo = (((2 * q) & 3) << 4) + ml;
                const int srcHi = (((2 * q + 1) & 3) << 4) + ml;
                const bool hiSel = (q >> 1) & 1;
                unsigned l0a = (unsigned)__shfl((int)pw[0][0], srcLo);
                unsigned l0b = (unsigned)__shfl((int)pw[1][0], srcLo);
                unsigned l1a = (unsigned)__shfl((int)pw[0][1], srcLo);
                unsigned l1b = (unsigned)__shfl((int)pw[1][1], srcLo);
                unsigned h0a = (unsigned)__shfl((int)pw[0][0], srcHi);
                unsigned h0b = (unsigned)__shfl((int)pw[1][0], srcHi);
                unsigned h1a = (unsigned)__shfl((int)pw[0][1], srcHi);
                unsigned h1b = (unsigned)__shfl((int)pw[1][1], srcHi);
                u32x4 wv4u = { hiSel ? l0b : l0a, hiSel ? l1b : l1a,
                               hiSel ? h0b : h0a, hiSel ? h1b : h1a };
                a2h[kk] = __builtin_bit_cast(bf16x8, wv4u);
            }

            // -- GEMM2 (bias-initialized accumulators) --
            f32x4 acc2h[8];
#pragma unroll
            for (int ot = 0; ot < 8; ot++) {
                bf16x8 B[4];
#pragma unroll
                for (int kk = 0; kk < 4; kk++)
                    B[kk] = *(const bf16x8*)(wbytes + LM2B + (ot * 16 + ml) * 256 + ((((kk * 4 + q) << 4)) ^ swzb));
                f32x4 acc = {bb2[ot], bb2[ot], bb2[ot], bb2[ot]};
#pragma unroll
                for (int kk = 0; kk < 4; kk++) acc = MFMA(a2h[kk], B[kk], acc);
                acc2h[ot] = acc;
            }

            // -- run walk for this half's rows [lo, lo+hcnt) --
            unsigned hm = (unsigned)((bmask >> lo) & 0xffffull) | 1u;
            if (hcnt < 16) hm &= (1u << hcnt) - 1u;
            while (hm) {
                int a = (int)__builtin_ctz(hm);
                hm &= hm - 1u;
                int b = hm ? (int)__builtin_ctz(hm) : hcnt;
                int c = __shfl(iv, lo + a);
                if (c != cur_c) {
                    if (cur_c >= 0) flushf();
                    cur_c = c;
                }
                float tmax = -1e30f;
#pragma unroll
                for (int rr = 0; rr < 4; rr++) {
                    int row = q * 4 + rr;
                    if (row >= a && row < b) tmax = fmaxf(tmax, lv4[rr]);
                }
                tmax = fmaxf(tmax, __shfl_xor(tmax, 16));
                tmax = fmaxf(tmax, __shfl_xor(tmax, 32));
                float m_new = fmaxf(m_run, tmax);
                float scf = __expf(m_run - m_new);
                d_run *= scf;
#pragma unroll
                for (int ot = 0; ot < 8; ot++) wacc[ot] *= scf;
                m_run = m_new;

                float wv4[4]; float dp = 0.f;
#pragma unroll
                for (int rr = 0; rr < 4; rr++) {
                    int row = q * 4 + rr;
                    float ww = (row >= a && row < b) ? __expf(lv4[rr] - m_run) : 0.f;
                    wv4[rr] = ww; dp += ww;
                }
                dp += __shfl_xor(dp, 16);
                dp += __shfl_xor(dp, 32);
                d_run += dp;
#pragma unroll
                for (int ot = 0; ot < 8; ot++) {
                    f32x4 acc = acc2h[ot];
                    wacc[ot] += wv4[0] * acc[0] + wv4[1] * acc[1]
                              + wv4[2] * acc[2] + wv4[3] * acc[3];
                }
            }
        }
    }

    if (cur_c >= 0) flushf();
    for (int z = emit_c; z < cw1; z++)   // trailing empty crystals
        *(float2*)&out[(size_t)z * 512 + h * 128 + lane * 2] = make_float2(0.f, 0.f);
}

// ---------------------------------------------------------------------------
extern "C" void kernel_launch(void* const* d_in, const int* in_sizes, int n_in,
                              void* d_out, int out_size, void* d_ws, size_t ws_size,
                              hipStream_t stream)
{
    const float* fea = (const float*)d_in[0];
    const float* cry = (const float*)d_in[1];
    const float* Wm1 = (const float*)d_in[2];
    const float* bm1 = (const float*)d_in[3];
    const float* Wm2 = (const float*)d_in[4];
    const float* bm2 = (const float*)d_in[5];
    const float* Wa1 = (const float*)d_in[6];
    const float* ba1 = (const float*)d_in[7];
    const float* Wa2 = (const float*)d_in[8];
    const float* ba2 = (const float*)d_in[9];
    const int* index = (const int*)d_in[10];

    const int N = in_sizes[0] / 128;      // 200000
    const int S = out_size / 512;         // 16384
    const int grid = 4 * ((S + CPB - 1) / CPB);

    const size_t wOff    = (size_t)SEG_BYTES;
    const size_t cryOff  = wOff + (size_t)W_BYTES;
    const size_t feaOff  = cryOff + (size_t)S * 256;     // S*128*2 B
    const size_t needSeg  = (size_t)SEG_BYTES;
    const size_t needW    = cryOff;
    const size_t needFull = feaOff + (size_t)N * 256;    // + N*128*2 B
    const bool segFits = (S + 1) <= SEG_INTS;

    if (segFits && ws_size >= needFull) {
        int* seg = (int*)d_ws;
        __bf16* wbp  = (__bf16*)((char*)d_ws + wOff);
        __bf16* cryb = (__bf16*)((char*)d_ws + cryOff);
        __bf16* feab = (__bf16*)((char*)d_ws + feaOff);
        seg_kernel<<<(S + 1 + 255) / 256, 256, 0, stream>>>(index, N, S, seg);
        prep_kernel<<<(W_ELEMS / 8 + 255) / 256, 256, 0, stream>>>(Wm1, Wm2, Wa1, Wa2, wbp);
        cast_kernel<<<(S * 16 + 255) / 256, 256, 0, stream>>>(cry, cryb, S * 16);
        cast_kernel<<<(N * 16 + 255) / 256, 256, 0, stream>>>(fea, feab, N * 16);
        fused4_kernel<true, true, true><<<grid, THREADS, 0, stream>>>(
            fea, cry, Wm1, bm1, Wm2, bm2, Wa1, ba1, Wa2, ba2,
            wbp, seg, feab, cryb, index, N, S, (float*)d_out);
    } else if (segFits && ws_size >= needW) {
        int* seg = (int*)d_ws;
        __bf16* wbp = (__bf16*)((char*)d_ws + wOff);
        seg_kernel<<<(S + 1 + 255) / 256, 256, 0, stream>>>(index, N, S, seg);
        prep_kernel<<<(W_ELEMS / 8 + 255) / 256, 256, 0, stream>>>(Wm1, Wm2, Wa1, Wa2, wbp);
        fused4_kernel<true, true, false><<<grid, THREADS, 0, stream>>>(
            fea, cry, Wm1, bm1, Wm2, bm2, Wa1, ba1, Wa2, ba2,
            wbp, seg, nullptr, nullptr, index, N, S, (float*)d_out);
    } else if (segFits && ws_size >= needSeg) {
        int* seg = (int*)d_ws;
        seg_kernel<<<(S + 1 + 255) / 256, 256, 0, stream>>>(index, N, S, seg);
        fused4_kernel<false, true, false><<<grid, THREADS, 0, stream>>>(
            fea, cry, Wm1, bm1, Wm2, bm2, Wa1, ba1, Wa2, ba2,
            nullptr, seg, nullptr, nullptr, index, N, S, (float*)d_out);
    } else {
        fused4_kernel<false, false, false><<<grid, THREADS, 0, stream>>>(
            fea, cry, Wm1, bm1, Wm2, bm2, Wa1, ba1, Wa2, ba2,
            nullptr, nullptr, nullptr, nullptr, index, N, S, (float*)d_out);
    }
}